// Round 5
// baseline (200.447 us; speedup 1.0000x reference)
//
#include <hip/hip_runtime.h>
#include <math.h>

// acc layout in d_ws (floats):
// [0]=sdf_sum [1]=eik_sum(M+N) [2]=morse_sum [3]=h_sum [4]=neigh_sum [5]=inter_sum
// d_ws + 256: packed cross-field, N x 16B (8 x f16: va.xyz, vb.xyz, pad, pad)
static constexpr int BLOCK = 256;
static constexpr int WAVES = BLOCK / 64;
static constexpr int KVAL = 4;

typedef float f4 __attribute__((ext_vector_type(4)));
typedef int i4 __attribute__((ext_vector_type(4)));
typedef unsigned int u4v __attribute__((ext_vector_type(4)));
union VV { u4v u4; _Float16 h[8]; };

__device__ __forceinline__ float ntl(const float* p) {
  return __builtin_nontemporal_load(p);
}
__device__ __forceinline__ f4 ntl4(const f4* p) {
  return __builtin_nontemporal_load(p);
}
__device__ __forceinline__ i4 nti4(const i4* p) {
  return __builtin_nontemporal_load(p);
}

__device__ __forceinline__ void norm3(float x, float y, float z,
                                      float& ox, float& oy, float& oz) {
  float inv = 1.0f / (sqrtf(x * x + y * y + z * z) + 1e-12f);
  ox = x * inv; oy = y * inv; oz = z * inv;
}

__device__ __forceinline__ void crossfield(const float* __restrict__ u,
                                           const float* __restrict__ v,
                                           const float* __restrict__ theta,
                                           int n, float va[3], float vb[3]) {
  float s, c;
  __sincosf(theta[n], &s, &c);
  float ux = u[3 * n], uy = u[3 * n + 1], uz = u[3 * n + 2];
  float vx = v[3 * n], vy = v[3 * n + 1], vz = v[3 * n + 2];
  norm3(ux * c + vx * s, uy * c + vy * s, uz * c + vz * s, va[0], va[1], va[2]);
  norm3(vx * c - ux * s, vy * c - uy * s, vz * c - uz * s, vb[0], vb[1], vb[2]);
}

template <int NV>
__device__ __forceinline__ void block_accum(float (&p)[NV], float* __restrict__ acc,
                                            const int (&slot)[NV]) {
#pragma unroll
  for (int off = 32; off > 0; off >>= 1)
#pragma unroll
    for (int q = 0; q < NV; ++q) p[q] += __shfl_down(p[q], off, 64);
  __shared__ float sm[WAVES][NV];
  int wave = threadIdx.x >> 6, lane = threadIdx.x & 63;
  if (lane == 0)
#pragma unroll
    for (int q = 0; q < NV; ++q) sm[wave][q] = p[q];
  __syncthreads();
  if (threadIdx.x == 0) {
#pragma unroll
    for (int q = 0; q < NV; ++q) {
      float t = 0.f;
#pragma unroll
      for (int w = 0; w < WAVES; ++w) t += sm[w][q];
      atomicAdd(&acc[slot[q]], t);
    }
  }
}

// ---- pass 1: ALL streaming terms (point + vertex) + cross-field store ------
__global__ __launch_bounds__(BLOCK) void pass1_kernel(
    const float* __restrict__ theta, const float* __restrict__ u,
    const float* __restrict__ v, u4v* __restrict__ vavb, int N,
    const float* __restrict__ pred, const float* __restrict__ pgrad,
    const float* __restrict__ mp, const float* __restrict__ grad,
    const float* __restrict__ H, const float* __restrict__ ngt,
    float* __restrict__ acc, int M) {
  int i = blockIdx.x * blockDim.x + threadIdx.x;
  float p[5] = {0.f, 0.f, 0.f, 0.f, 0.f};  // sdf, eik, morse, halign, inter
  if (i < M) {
    p[4] = __expf(-100.0f * fabsf(ntl(pred + i)));
    float gx = ntl(pgrad + 3 * i), gy = ntl(pgrad + 3 * i + 1),
          gz = ntl(pgrad + 3 * i + 2);
    p[1] = fabsf(sqrtf(gx * gx + gy * gy + gz * gz) - 1.0f);
  }
  if (i < N) {
    p[0] = fabsf(ntl(mp + i));
    float gx = ntl(grad + 3 * i), gy = ntl(grad + 3 * i + 1),
          gz = ntl(grad + 3 * i + 2);
    p[1] += fabsf(sqrtf(gx * gx + gy * gy + gz * gz) - 1.0f);

    float h[9];
#pragma unroll
    for (int q = 0; q < 9; ++q) h[q] = ntl(H + 9 * (size_t)i + q);
    float n0 = ntl(ngt + 3 * i), n1 = ntl(ngt + 3 * i + 1), n2 = ntl(ngt + 3 * i + 2);
    p[2] = fabsf(n0 * h[0] + n1 * h[3] + n2 * h[6]) +
           fabsf(n0 * h[1] + n1 * h[4] + n2 * h[7]) +
           fabsf(n0 * h[2] + n1 * h[5] + n2 * h[8]);

    float va[3], vb[3];
    crossfield(u, v, theta, i, va, vb);
    {
      float a0 = va[0] * h[0] + va[1] * h[3] + va[2] * h[6];
      float a1 = va[0] * h[1] + va[1] * h[4] + va[2] * h[7];
      float a2 = va[0] * h[2] + va[1] * h[5] + va[2] * h[8];
      float b0 = vb[0] * h[0] + vb[1] * h[3] + vb[2] * h[6];
      float b1 = vb[0] * h[1] + vb[1] * h[4] + vb[2] * h[7];
      float b2 = vb[0] * h[2] + vb[1] * h[5] + vb[2] * h[8];
      p[3] = fabsf(a1 * va[2] - a2 * va[1]) + fabsf(a2 * va[0] - a0 * va[2]) +
             fabsf(a0 * va[1] - a1 * va[0]) + fabsf(b1 * vb[2] - b2 * vb[1]) +
             fabsf(b2 * vb[0] - b0 * vb[2]) + fabsf(b0 * vb[1] - b1 * vb[0]);
    }
    VV w;
    w.h[0] = (_Float16)va[0]; w.h[1] = (_Float16)va[1]; w.h[2] = (_Float16)va[2];
    w.h[3] = (_Float16)vb[0]; w.h[4] = (_Float16)vb[1]; w.h[5] = (_Float16)vb[2];
    w.h[6] = (_Float16)0.f;   w.h[7] = (_Float16)0.f;
    vavb[i] = w.u4;
  }
  const int slot[5] = {0, 1, 2, 3, 5};
  block_accum<5>(p, acc, slot);
}

// ---- pass 2: neighbor-consistency term only (gather-bound, lean) -----------
__global__ __launch_bounds__(BLOCK) void pass2_kernel(
    const u4v* __restrict__ vavb, const float* __restrict__ rot,
    const i4* __restrict__ nbr, float* __restrict__ acc, int N) {
  int n = blockIdx.x * blockDim.x + threadIdx.x;
  float p[1] = {0.f};
  if (n < N) {
    i4 jj = nti4(nbr + n);
    int js[4] = {jj.x, jj.y, jj.z, jj.w};
    // issue all gathers + self load first (max MLP)
    VV wn[4];
#pragma unroll
    for (int k = 0; k < KVAL; ++k) wn[k].u4 = vavb[js[k]];
    VV ws; ws.u4 = vavb[n];
    // rot: 9 nontemporal float4 loads (independent stream)
    float r[36];
    const f4* rv = (const f4*)(rot + (size_t)n * 36);
#pragma unroll
    for (int q = 0; q < 9; ++q) {
      f4 t = ntl4(rv + q);
      r[4 * q] = t.x; r[4 * q + 1] = t.y; r[4 * q + 2] = t.z; r[4 * q + 3] = t.w;
    }
    float va[3] = {(float)ws.h[0], (float)ws.h[1], (float)ws.h[2]};
    float vb[3] = {(float)ws.h[3], (float)ws.h[4], (float)ws.h[5]};
    float nsum = 0.f;
#pragma unroll
    for (int k = 0; k < KVAL; ++k) {
      float vaj[3] = {(float)wn[k].h[0], (float)wn[k].h[1], (float)wn[k].h[2]};
      float vbj[3] = {(float)wn[k].h[3], (float)wn[k].h[4], (float)wn[k].h[5]};
      const float* R = r + 9 * k;
      float wa0 = R[0] * vaj[0] + R[1] * vaj[1] + R[2] * vaj[2];
      float wa1 = R[3] * vaj[0] + R[4] * vaj[1] + R[5] * vaj[2];
      float wa2 = R[6] * vaj[0] + R[7] * vaj[1] + R[8] * vaj[2];
      float wb0 = R[0] * vbj[0] + R[1] * vbj[1] + R[2] * vbj[2];
      float wb1 = R[3] * vbj[0] + R[4] * vbj[1] + R[5] * vbj[2];
      float wb2 = R[6] * vbj[0] + R[7] * vbj[1] + R[8] * vbj[2];
      nsum += fabsf(va[0] * wa0 + va[1] * wa1 + va[2] * wa2) +
              fabsf(va[0] * wb0 + va[1] * wb1 + va[2] * wb2) +
              fabsf(vb[0] * wa0 + vb[1] * wa1 + vb[2] * wa2) +
              fabsf(vb[0] * wb0 + vb[1] * wb1 + vb[2] * wb2) - 2.0f;
    }
    p[0] = nsum;
  }
  const int slot[1] = {4};
  block_accum<1>(p, acc, slot);
}

// ---------------- fallback (recompute) if ws too small ----------------------
__global__ __launch_bounds__(BLOCK) void vertex_kernel(
    const float* __restrict__ mp, const float* __restrict__ grad,
    const float* __restrict__ H, const float* __restrict__ ngt,
    const float* __restrict__ theta, const float* __restrict__ u,
    const float* __restrict__ v, const float* __restrict__ rot,
    const int* __restrict__ nbr, float* __restrict__ acc, int N) {
  int n = blockIdx.x * blockDim.x + threadIdx.x;
  float p[5] = {0.f, 0.f, 0.f, 0.f, 0.f};
  if (n < N) {
    p[0] = fabsf(mp[n]);
    float gx = grad[3 * n], gy = grad[3 * n + 1], gz = grad[3 * n + 2];
    p[1] = fabsf(sqrtf(gx * gx + gy * gy + gz * gz) - 1.0f);
    float h[9];
#pragma unroll
    for (int i = 0; i < 9; ++i) h[i] = H[9 * (size_t)n + i];
    float n0 = ngt[3 * n], n1 = ngt[3 * n + 1], n2 = ngt[3 * n + 2];
    p[2] = fabsf(n0 * h[0] + n1 * h[3] + n2 * h[6]) +
           fabsf(n0 * h[1] + n1 * h[4] + n2 * h[7]) +
           fabsf(n0 * h[2] + n1 * h[5] + n2 * h[8]);
    float va[3], vb[3];
    crossfield(u, v, theta, n, va, vb);
    {
      float a0 = va[0] * h[0] + va[1] * h[3] + va[2] * h[6];
      float a1 = va[0] * h[1] + va[1] * h[4] + va[2] * h[7];
      float a2 = va[0] * h[2] + va[1] * h[5] + va[2] * h[8];
      float b0 = vb[0] * h[0] + vb[1] * h[3] + vb[2] * h[6];
      float b1 = vb[0] * h[1] + vb[1] * h[4] + vb[2] * h[7];
      float b2 = vb[0] * h[2] + vb[1] * h[5] + vb[2] * h[8];
      p[3] = fabsf(a1 * va[2] - a2 * va[1]) + fabsf(a2 * va[0] - a0 * va[2]) +
             fabsf(a0 * va[1] - a1 * va[0]) + fabsf(b1 * vb[2] - b2 * vb[1]) +
             fabsf(b2 * vb[0] - b0 * vb[2]) + fabsf(b0 * vb[1] - b1 * vb[0]);
    }
    float nsum = 0.f;
    const float* R = rot + (size_t)n * (KVAL * 9);
#pragma unroll
    for (int k = 0; k < KVAL; ++k) {
      int j = nbr[KVAL * (size_t)n + k];
      float vaj[3], vbj[3];
      crossfield(u, v, theta, j, vaj, vbj);
      float r0 = R[9 * k + 0], r1 = R[9 * k + 1], r2 = R[9 * k + 2];
      float r3 = R[9 * k + 3], r4 = R[9 * k + 4], r5 = R[9 * k + 5];
      float r6 = R[9 * k + 6], r7 = R[9 * k + 7], r8 = R[9 * k + 8];
      float wa0 = r0 * vaj[0] + r1 * vaj[1] + r2 * vaj[2];
      float wa1 = r3 * vaj[0] + r4 * vaj[1] + r5 * vaj[2];
      float wa2 = r6 * vaj[0] + r7 * vaj[1] + r8 * vaj[2];
      float wb0 = r0 * vbj[0] + r1 * vbj[1] + r2 * vbj[2];
      float wb1 = r3 * vbj[0] + r4 * vbj[1] + r5 * vbj[2];
      float wb2 = r6 * vbj[0] + r7 * vbj[1] + r8 * vbj[2];
      nsum += fabsf(va[0] * wa0 + va[1] * wa1 + va[2] * wa2) +
              fabsf(va[0] * wb0 + va[1] * wb1 + va[2] * wb2) +
              fabsf(vb[0] * wa0 + vb[1] * wa1 + vb[2] * wa2) +
              fabsf(vb[0] * wb0 + vb[1] * wb1 + vb[2] * wb2) - 2.0f;
    }
    p[4] = nsum;
  }
  const int slot[5] = {0, 1, 2, 3, 4};
  block_accum<5>(p, acc, slot);
}

__global__ __launch_bounds__(BLOCK) void point_kernel(
    const float* __restrict__ pred, const float* __restrict__ grad,
    float* __restrict__ acc, int M) {
  int i = blockIdx.x * blockDim.x + threadIdx.x;
  float p[2] = {0.f, 0.f};
  if (i < M) {
    p[0] = __expf(-100.0f * fabsf(pred[i]));
    float gx = grad[3 * i], gy = grad[3 * i + 1], gz = grad[3 * i + 2];
    p[1] = fabsf(sqrtf(gx * gx + gy * gy + gz * gz) - 1.0f);
  }
  const int slot[2] = {5, 1};
  block_accum<2>(p, acc, slot);
}

__global__ void finalize_kernel(const float* __restrict__ acc, float* __restrict__ out,
                                int N, int M) {
  if (threadIdx.x == 0 && blockIdx.x == 0) {
    float sdf = acc[0] / (float)N;
    float eik = acc[1] / (float)(N + M);
    float morse = 0.5f * acc[2] / (3.0f * (float)N);
    float th = 0.5f * acc[3] / (3.0f * (float)N);
    float nb = acc[4] / ((float)N * (float)KVAL);
    float inter = acc[5] / (float)M;
    float loss = 7000.0f * sdf + 600.0f * inter + 50.0f * eik + 3.0f * morse +
                 10.0f * th + 30.0f * nb;
    out[0] = loss; out[1] = sdf; out[2] = inter; out[3] = eik;
    out[4] = morse; out[5] = th; out[6] = nb;
  }
}

extern "C" void kernel_launch(void* const* d_in, const int* in_sizes, int n_in,
                              void* d_out, int out_size, void* d_ws, size_t ws_size,
                              hipStream_t stream) {
  const float* mp    = (const float*)d_in[0];
  const float* npred = (const float*)d_in[1];
  const float* grad  = (const float*)d_in[2];
  const float* ngrad = (const float*)d_in[3];
  const float* H     = (const float*)d_in[4];
  const float* ngt   = (const float*)d_in[5];
  const float* theta = (const float*)d_in[6];
  const float* u     = (const float*)d_in[7];
  const float* v     = (const float*)d_in[8];
  const float* rot   = (const float*)d_in[9];
  const int*   nbr   = (const int*)d_in[10];
  float* acc = (float*)d_ws;
  float* out = (float*)d_out;

  int N = in_sizes[0];
  int M = in_sizes[1];

  (void)hipMemsetAsync(acc, 0, 6 * sizeof(float), stream);

  size_t need = 256 + (size_t)N * 16;
  if (ws_size >= need) {
    u4v* vavb = (u4v*)((char*)d_ws + 256);
    int nm = (N > M) ? N : M;
    pass1_kernel<<<(nm + BLOCK - 1) / BLOCK, BLOCK, 0, stream>>>(
        theta, u, v, vavb, N, npred, ngrad, mp, grad, H, ngt, acc, M);
    pass2_kernel<<<(N + BLOCK - 1) / BLOCK, BLOCK, 0, stream>>>(
        vavb, rot, (const i4*)nbr, acc, N);
  } else {
    vertex_kernel<<<(N + BLOCK - 1) / BLOCK, BLOCK, 0, stream>>>(
        mp, grad, H, ngt, theta, u, v, rot, nbr, acc, N);
    point_kernel<<<(M + BLOCK - 1) / BLOCK, BLOCK, 0, stream>>>(npred, ngrad, acc, M);
  }
  finalize_kernel<<<1, 64, 0, stream>>>(acc, out, N, M);
}

// Round 6
// 93.444 us; speedup vs baseline: 2.1451x; 2.1451x over previous
//
#include <hip/hip_runtime.h>
#include <math.h>

// ws layout: [0,24): acc (fallback only). [256, 256+16N): packed cross-field
// (8 x f16 per vertex). Then part1 (5*nb1 floats), part2 (nb2 floats).
static constexpr int BLOCK = 256;
static constexpr int WAVES = BLOCK / 64;
static constexpr int KVAL = 4;

typedef float f4 __attribute__((ext_vector_type(4)));
typedef int i4 __attribute__((ext_vector_type(4)));
typedef unsigned int u4v __attribute__((ext_vector_type(4)));
union VV { u4v u4; _Float16 h[8]; };
union F4S { f4 v; float f[4]; };
union F12 { f4 v[3]; float f[12]; };
union F36 { f4 v[9]; float f[36]; };

__device__ __forceinline__ float ntl(const float* p) {
  return __builtin_nontemporal_load(p);
}
__device__ __forceinline__ f4 ntl4(const f4* p) {
  return __builtin_nontemporal_load(p);
}
__device__ __forceinline__ i4 nti4(const i4* p) {
  return __builtin_nontemporal_load(p);
}

__device__ __forceinline__ void norm3(float x, float y, float z,
                                      float& ox, float& oy, float& oz) {
  float inv = 1.0f / (sqrtf(x * x + y * y + z * z) + 1e-12f);
  ox = x * inv; oy = y * inv; oz = z * inv;
}

__device__ __forceinline__ void crossfield(const float* __restrict__ u,
                                           const float* __restrict__ v,
                                           const float* __restrict__ theta,
                                           int n, float va[3], float vb[3]) {
  float s, c;
  __sincosf(theta[n], &s, &c);
  float ux = u[3 * n], uy = u[3 * n + 1], uz = u[3 * n + 2];
  float vx = v[3 * n], vy = v[3 * n + 1], vz = v[3 * n + 2];
  norm3(ux * c + vx * s, uy * c + vy * s, uz * c + vz * s, va[0], va[1], va[2]);
  norm3(vx * c - ux * s, vy * c - uy * s, vz * c - uz * s, vb[0], vb[1], vb[2]);
}

// block-wide reduce of NV floats; total lands in thread 0's p[]
template <int NV>
__device__ __forceinline__ void block_reduce(float (&p)[NV]) {
#pragma unroll
  for (int off = 32; off > 0; off >>= 1)
#pragma unroll
    for (int q = 0; q < NV; ++q) p[q] += __shfl_down(p[q], off, 64);
  __shared__ float sm[WAVES][NV];
  int wave = threadIdx.x >> 6, lane = threadIdx.x & 63;
  if (lane == 0)
#pragma unroll
    for (int q = 0; q < NV; ++q) sm[wave][q] = p[q];
  __syncthreads();
  if (threadIdx.x == 0) {
#pragma unroll
    for (int q = 0; q < NV; ++q) {
      float t = 0.f;
#pragma unroll
      for (int w = 1; w < WAVES; ++w) t += sm[w][q];
      p[q] += t;
    }
  }
}

// per-vertex streaming terms; p = {sdf, eik, morse, halign, inter}
__device__ __forceinline__ void vterm(float mpv, float gx, float gy, float gz,
                                      const float* h, float n0, float n1, float n2,
                                      float th, float ux, float uy, float uz,
                                      float vx, float vy, float vz,
                                      u4v* __restrict__ vavb, int n, float (&p)[5]) {
  p[0] += fabsf(mpv);
  p[1] += fabsf(sqrtf(gx * gx + gy * gy + gz * gz) - 1.0f);
  p[2] += fabsf(n0 * h[0] + n1 * h[3] + n2 * h[6]) +
          fabsf(n0 * h[1] + n1 * h[4] + n2 * h[7]) +
          fabsf(n0 * h[2] + n1 * h[5] + n2 * h[8]);
  float s, c;
  __sincosf(th, &s, &c);
  float va[3], vb[3];
  norm3(ux * c + vx * s, uy * c + vy * s, uz * c + vz * s, va[0], va[1], va[2]);
  norm3(vx * c - ux * s, vy * c - uy * s, vz * c - uz * s, vb[0], vb[1], vb[2]);
  {
    float a0 = va[0] * h[0] + va[1] * h[3] + va[2] * h[6];
    float a1 = va[0] * h[1] + va[1] * h[4] + va[2] * h[7];
    float a2 = va[0] * h[2] + va[1] * h[5] + va[2] * h[8];
    float b0 = vb[0] * h[0] + vb[1] * h[3] + vb[2] * h[6];
    float b1 = vb[0] * h[1] + vb[1] * h[4] + vb[2] * h[7];
    float b2 = vb[0] * h[2] + vb[1] * h[5] + vb[2] * h[8];
    p[3] += fabsf(a1 * va[2] - a2 * va[1]) + fabsf(a2 * va[0] - a0 * va[2]) +
            fabsf(a0 * va[1] - a1 * va[0]) + fabsf(b1 * vb[2] - b2 * vb[1]) +
            fabsf(b2 * vb[0] - b0 * vb[2]) + fabsf(b0 * vb[1] - b1 * vb[0]);
  }
  VV w;
  w.h[0] = (_Float16)va[0]; w.h[1] = (_Float16)va[1]; w.h[2] = (_Float16)va[2];
  w.h[3] = (_Float16)vb[0]; w.h[4] = (_Float16)vb[1]; w.h[5] = (_Float16)vb[2];
  w.h[6] = (_Float16)0.f;   w.h[7] = (_Float16)0.f;
  vavb[n] = w.u4;
}

// ---- pass 1: all streaming terms, 4 items/thread, float4 loads, no atomics -
__global__ __launch_bounds__(BLOCK, 2) void pass1_kernel(
    const float* __restrict__ theta, const float* __restrict__ u,
    const float* __restrict__ v, u4v* __restrict__ vavb, int N,
    const float* __restrict__ pred, const float* __restrict__ pgrad,
    const float* __restrict__ mp, const float* __restrict__ grad,
    const float* __restrict__ H, const float* __restrict__ ngt,
    float* __restrict__ part1, int nb1, int M) {
  long t = blockIdx.x * (long)BLOCK + threadIdx.x;
  long base = 4 * t;
  float p[5] = {0.f, 0.f, 0.f, 0.f, 0.f};  // sdf, eik, morse, halign, inter
  // ---- point terms
  if (base + 3 < M) {
    F4S pr; pr.v = ntl4((const f4*)(pred + base));
    F12 pg;
#pragma unroll
    for (int q = 0; q < 3; ++q) pg.v[q] = ntl4((const f4*)(pgrad + 3 * base) + q);
#pragma unroll
    for (int k = 0; k < 4; ++k) {
      p[4] += __expf(-100.0f * fabsf(pr.f[k]));
      float gx = pg.f[3 * k], gy = pg.f[3 * k + 1], gz = pg.f[3 * k + 2];
      p[1] += fabsf(sqrtf(gx * gx + gy * gy + gz * gz) - 1.0f);
    }
  } else if (base < M) {
    for (int k = 0; k < 4; ++k) {
      long i = base + k;
      if (i < M) {
        p[4] += __expf(-100.0f * fabsf(pred[i]));
        float gx = pgrad[3 * i], gy = pgrad[3 * i + 1], gz = pgrad[3 * i + 2];
        p[1] += fabsf(sqrtf(gx * gx + gy * gy + gz * gz) - 1.0f);
      }
    }
  }
  // ---- vertex terms
  if (base + 3 < N) {
    F4S mpv; mpv.v = ntl4((const f4*)(mp + base));
    F12 g;
#pragma unroll
    for (int q = 0; q < 3; ++q) g.v[q] = ntl4((const f4*)(grad + 3 * base) + q);
    F36 h;
#pragma unroll
    for (int q = 0; q < 9; ++q) h.v[q] = ntl4((const f4*)(H + 9 * base) + q);
    F12 ng;
#pragma unroll
    for (int q = 0; q < 3; ++q) ng.v[q] = ntl4((const f4*)(ngt + 3 * base) + q);
    F4S th; th.v = ntl4((const f4*)(theta + base));
    F12 uu;
#pragma unroll
    for (int q = 0; q < 3; ++q) uu.v[q] = ntl4((const f4*)(u + 3 * base) + q);
    F12 vv;
#pragma unroll
    for (int q = 0; q < 3; ++q) vv.v[q] = ntl4((const f4*)(v + 3 * base) + q);
#pragma unroll
    for (int k = 0; k < 4; ++k)
      vterm(mpv.f[k], g.f[3 * k], g.f[3 * k + 1], g.f[3 * k + 2], h.f + 9 * k,
            ng.f[3 * k], ng.f[3 * k + 1], ng.f[3 * k + 2], th.f[k],
            uu.f[3 * k], uu.f[3 * k + 1], uu.f[3 * k + 2],
            vv.f[3 * k], vv.f[3 * k + 1], vv.f[3 * k + 2],
            vavb, (int)(base + k), p);
  } else if (base < N) {
    for (int k = 0; k < 4; ++k) {
      long i = base + k;
      if (i < N) {
        float hh[9];
#pragma unroll
        for (int q = 0; q < 9; ++q) hh[q] = H[9 * i + q];
        vterm(mp[i], grad[3 * i], grad[3 * i + 1], grad[3 * i + 2], hh,
              ngt[3 * i], ngt[3 * i + 1], ngt[3 * i + 2], theta[i],
              u[3 * i], u[3 * i + 1], u[3 * i + 2],
              v[3 * i], v[3 * i + 1], v[3 * i + 2], vavb, (int)i, p);
      }
    }
  }
  block_reduce<5>(p);
  if (threadIdx.x == 0) {
#pragma unroll
    for (int q = 0; q < 5; ++q) part1[q * nb1 + blockIdx.x] = p[q];
  }
}

// ---- pass 2: neighbor-consistency (gather), no atomics ---------------------
__global__ __launch_bounds__(BLOCK) void pass2_kernel(
    const u4v* __restrict__ vavb, const float* __restrict__ rot,
    const i4* __restrict__ nbr, float* __restrict__ part2, int N) {
  int n = blockIdx.x * BLOCK + threadIdx.x;
  float p[1] = {0.f};
  if (n < N) {
    i4 jj = nti4(nbr + n);
    int js[4] = {jj.x, jj.y, jj.z, jj.w};
    VV wn[4];
#pragma unroll
    for (int k = 0; k < KVAL; ++k) wn[k].u4 = vavb[js[k]];
    VV ws; ws.u4 = vavb[n];
    float r[36];
    const f4* rv = (const f4*)(rot + (size_t)n * 36);
#pragma unroll
    for (int q = 0; q < 9; ++q) {
      f4 t = ntl4(rv + q);
      r[4 * q] = t.x; r[4 * q + 1] = t.y; r[4 * q + 2] = t.z; r[4 * q + 3] = t.w;
    }
    float va[3] = {(float)ws.h[0], (float)ws.h[1], (float)ws.h[2]};
    float vb[3] = {(float)ws.h[3], (float)ws.h[4], (float)ws.h[5]};
    float nsum = 0.f;
#pragma unroll
    for (int k = 0; k < KVAL; ++k) {
      float vaj[3] = {(float)wn[k].h[0], (float)wn[k].h[1], (float)wn[k].h[2]};
      float vbj[3] = {(float)wn[k].h[3], (float)wn[k].h[4], (float)wn[k].h[5]};
      const float* R = r + 9 * k;
      float wa0 = R[0] * vaj[0] + R[1] * vaj[1] + R[2] * vaj[2];
      float wa1 = R[3] * vaj[0] + R[4] * vaj[1] + R[5] * vaj[2];
      float wa2 = R[6] * vaj[0] + R[7] * vaj[1] + R[8] * vaj[2];
      float wb0 = R[0] * vbj[0] + R[1] * vbj[1] + R[2] * vbj[2];
      float wb1 = R[3] * vbj[0] + R[4] * vbj[1] + R[5] * vbj[2];
      float wb2 = R[6] * vbj[0] + R[7] * vbj[1] + R[8] * vbj[2];
      nsum += fabsf(va[0] * wa0 + va[1] * wa1 + va[2] * wa2) +
              fabsf(va[0] * wb0 + va[1] * wb1 + va[2] * wb2) +
              fabsf(vb[0] * wa0 + vb[1] * wa1 + vb[2] * wa2) +
              fabsf(vb[0] * wb0 + vb[1] * wb1 + vb[2] * wb2) - 2.0f;
    }
    p[0] = nsum;
  }
  block_reduce<1>(p);
  if (threadIdx.x == 0) part2[blockIdx.x] = p[0];
}

// ---- finalize: reduce partials, compute weighted loss ----------------------
__global__ __launch_bounds__(BLOCK) void finalize_fast(
    const float* __restrict__ part1, int nb1, const float* __restrict__ part2,
    int nb2, float* __restrict__ out, int N, int M) {
  float s[6] = {0.f, 0.f, 0.f, 0.f, 0.f, 0.f};
  for (int b = threadIdx.x; b < nb1; b += BLOCK) {
#pragma unroll
    for (int q = 0; q < 5; ++q) s[q] += part1[q * nb1 + b];
  }
  for (int b = threadIdx.x; b < nb2; b += BLOCK) s[5] += part2[b];
  block_reduce<6>(s);
  if (threadIdx.x == 0) {
    float sdf = s[0] / (float)N;
    float eik = s[1] / (float)(N + M);
    float morse = 0.5f * s[2] / (3.0f * (float)N);
    float th = 0.5f * s[3] / (3.0f * (float)N);
    float inter = s[4] / (float)M;
    float nb = s[5] / ((float)N * (float)KVAL);
    float loss = 7000.0f * sdf + 600.0f * inter + 50.0f * eik + 3.0f * morse +
                 10.0f * th + 30.0f * nb;
    out[0] = loss; out[1] = sdf; out[2] = inter; out[3] = eik;
    out[4] = morse; out[5] = th; out[6] = nb;
  }
}

// ---------------- fallback path (atomics) if ws too small -------------------
__global__ __launch_bounds__(BLOCK) void vertex_kernel(
    const float* __restrict__ mp, const float* __restrict__ grad,
    const float* __restrict__ H, const float* __restrict__ ngt,
    const float* __restrict__ theta, const float* __restrict__ u,
    const float* __restrict__ v, const float* __restrict__ rot,
    const int* __restrict__ nbr, float* __restrict__ acc, int N) {
  int n = blockIdx.x * blockDim.x + threadIdx.x;
  float p[5] = {0.f, 0.f, 0.f, 0.f, 0.f};
  if (n < N) {
    float hh[9];
#pragma unroll
    for (int i = 0; i < 9; ++i) hh[i] = H[9 * (size_t)n + i];
    // dummy vavb target not available: inline the terms
    p[0] = fabsf(mp[n]);
    float gx = grad[3 * n], gy = grad[3 * n + 1], gz = grad[3 * n + 2];
    p[1] = fabsf(sqrtf(gx * gx + gy * gy + gz * gz) - 1.0f);
    float n0 = ngt[3 * n], n1 = ngt[3 * n + 1], n2 = ngt[3 * n + 2];
    p[2] = fabsf(n0 * hh[0] + n1 * hh[3] + n2 * hh[6]) +
           fabsf(n0 * hh[1] + n1 * hh[4] + n2 * hh[7]) +
           fabsf(n0 * hh[2] + n1 * hh[5] + n2 * hh[8]);
    float va[3], vb[3];
    crossfield(u, v, theta, n, va, vb);
    {
      float a0 = va[0] * hh[0] + va[1] * hh[3] + va[2] * hh[6];
      float a1 = va[0] * hh[1] + va[1] * hh[4] + va[2] * hh[7];
      float a2 = va[0] * hh[2] + va[1] * hh[5] + va[2] * hh[8];
      float b0 = vb[0] * hh[0] + vb[1] * hh[3] + vb[2] * hh[6];
      float b1 = vb[0] * hh[1] + vb[1] * hh[4] + vb[2] * hh[7];
      float b2 = vb[0] * hh[2] + vb[1] * hh[5] + vb[2] * hh[8];
      p[3] = fabsf(a1 * va[2] - a2 * va[1]) + fabsf(a2 * va[0] - a0 * va[2]) +
             fabsf(a0 * va[1] - a1 * va[0]) + fabsf(b1 * vb[2] - b2 * vb[1]) +
             fabsf(b2 * vb[0] - b0 * vb[2]) + fabsf(b0 * vb[1] - b1 * vb[0]);
    }
    float nsum = 0.f;
    const float* R = rot + (size_t)n * (KVAL * 9);
#pragma unroll
    for (int k = 0; k < KVAL; ++k) {
      int j = nbr[KVAL * (size_t)n + k];
      float vaj[3], vbj[3];
      crossfield(u, v, theta, j, vaj, vbj);
      float r0 = R[9 * k + 0], r1 = R[9 * k + 1], r2 = R[9 * k + 2];
      float r3 = R[9 * k + 3], r4 = R[9 * k + 4], r5 = R[9 * k + 5];
      float r6 = R[9 * k + 6], r7 = R[9 * k + 7], r8 = R[9 * k + 8];
      float wa0 = r0 * vaj[0] + r1 * vaj[1] + r2 * vaj[2];
      float wa1 = r3 * vaj[0] + r4 * vaj[1] + r5 * vaj[2];
      float wa2 = r6 * vaj[0] + r7 * vaj[1] + r8 * vaj[2];
      float wb0 = r0 * vbj[0] + r1 * vbj[1] + r2 * vbj[2];
      float wb1 = r3 * vbj[0] + r4 * vbj[1] + r5 * vbj[2];
      float wb2 = r6 * vbj[0] + r7 * vbj[1] + r8 * vbj[2];
      nsum += fabsf(va[0] * wa0 + va[1] * wa1 + va[2] * wa2) +
              fabsf(va[0] * wb0 + va[1] * wb1 + va[2] * wb2) +
              fabsf(vb[0] * wa0 + vb[1] * wa1 + vb[2] * wa2) +
              fabsf(vb[0] * wb0 + vb[1] * wb1 + vb[2] * wb2) - 2.0f;
    }
    p[4] = nsum;
  }
  block_reduce<5>(p);
  if (threadIdx.x == 0) {
    atomicAdd(&acc[0], p[0]); atomicAdd(&acc[1], p[1]); atomicAdd(&acc[2], p[2]);
    atomicAdd(&acc[3], p[3]); atomicAdd(&acc[4], p[4]);
  }
}

__global__ __launch_bounds__(BLOCK) void point_kernel(
    const float* __restrict__ pred, const float* __restrict__ grad,
    float* __restrict__ acc, int M) {
  int i = blockIdx.x * blockDim.x + threadIdx.x;
  float p[2] = {0.f, 0.f};
  if (i < M) {
    p[0] = __expf(-100.0f * fabsf(pred[i]));
    float gx = grad[3 * i], gy = grad[3 * i + 1], gz = grad[3 * i + 2];
    p[1] = fabsf(sqrtf(gx * gx + gy * gy + gz * gz) - 1.0f);
  }
  block_reduce<2>(p);
  if (threadIdx.x == 0) {
    atomicAdd(&acc[5], p[0]); atomicAdd(&acc[1], p[1]);
  }
}

__global__ void finalize_acc(const float* __restrict__ acc, float* __restrict__ out,
                             int N, int M) {
  if (threadIdx.x == 0 && blockIdx.x == 0) {
    float sdf = acc[0] / (float)N;
    float eik = acc[1] / (float)(N + M);
    float morse = 0.5f * acc[2] / (3.0f * (float)N);
    float th = 0.5f * acc[3] / (3.0f * (float)N);
    float nb = acc[4] / ((float)N * (float)KVAL);
    float inter = acc[5] / (float)M;
    float loss = 7000.0f * sdf + 600.0f * inter + 50.0f * eik + 3.0f * morse +
                 10.0f * th + 30.0f * nb;
    out[0] = loss; out[1] = sdf; out[2] = inter; out[3] = eik;
    out[4] = morse; out[5] = th; out[6] = nb;
  }
}

extern "C" void kernel_launch(void* const* d_in, const int* in_sizes, int n_in,
                              void* d_out, int out_size, void* d_ws, size_t ws_size,
                              hipStream_t stream) {
  const float* mp    = (const float*)d_in[0];
  const float* npred = (const float*)d_in[1];
  const float* grad  = (const float*)d_in[2];
  const float* ngrad = (const float*)d_in[3];
  const float* H     = (const float*)d_in[4];
  const float* ngt   = (const float*)d_in[5];
  const float* theta = (const float*)d_in[6];
  const float* u     = (const float*)d_in[7];
  const float* v     = (const float*)d_in[8];
  const float* rot   = (const float*)d_in[9];
  const int*   nbr   = (const int*)d_in[10];
  float* out = (float*)d_out;

  int N = in_sizes[0];
  int M = in_sizes[1];
  int mx = (N > M) ? N : M;
  int ngroups = (mx + 3) / 4;
  int nb1 = (ngroups + BLOCK - 1) / BLOCK;
  int nb2 = (N + BLOCK - 1) / BLOCK;

  size_t need = 256 + (size_t)N * 16 + (size_t)(5 * nb1 + nb2) * 4;
  if (ws_size >= need) {
    u4v* vavb   = (u4v*)((char*)d_ws + 256);
    float* part1 = (float*)((char*)d_ws + 256 + (size_t)N * 16);
    float* part2 = part1 + (size_t)5 * nb1;
    pass1_kernel<<<nb1, BLOCK, 0, stream>>>(
        theta, u, v, vavb, N, npred, ngrad, mp, grad, H, ngt, part1, nb1, M);
    pass2_kernel<<<nb2, BLOCK, 0, stream>>>(
        vavb, rot, (const i4*)nbr, part2, N);
    finalize_fast<<<1, BLOCK, 0, stream>>>(part1, nb1, part2, nb2, out, N, M);
  } else {
    float* acc = (float*)d_ws;
    (void)hipMemsetAsync(acc, 0, 6 * sizeof(float), stream);
    vertex_kernel<<<(N + BLOCK - 1) / BLOCK, BLOCK, 0, stream>>>(
        mp, grad, H, ngt, theta, u, v, rot, nbr, acc, N);
    point_kernel<<<(M + BLOCK - 1) / BLOCK, BLOCK, 0, stream>>>(npred, ngrad, acc, M);
    finalize_acc<<<1, 64, 0, stream>>>(acc, out, N, M);
  }
}